// Round 11
// baseline (1052.610 us; speedup 1.0000x reference)
//
#include <hip/hip_runtime.h>
#include <hip/hip_bf16.h>

#define NN 10000
#define NPAD 10048   // 157 * 64
#define EE 320000
#define DD 256
#define LL 5

typedef __bf16 bf16x8 __attribute__((ext_vector_type(8)));
typedef __bf16 bf16x4 __attribute__((ext_vector_type(4)));
typedef float f32x4 __attribute__((ext_vector_type(4)));

__device__ __forceinline__ void gload_lds16(const void* g, void* l) {
    __builtin_amdgcn_global_load_lds(
        (const __attribute__((address_space(1))) void*)g,
        (__attribute__((address_space(3))) void*)l, 16, 0, 0);
}

// ---------------- setup kernels ----------------

// merged elementwise prep: whh conv, x conv, pad-zero, deg-zero
__global__ void prep_k(const float* __restrict__ w_hh, const float* __restrict__ x,
                       __bf16* __restrict__ whhb,
                       float* __restrict__ hb, __bf16* __restrict__ hbfA,
                       __bf16* __restrict__ hbfB, int* __restrict__ deg) {
    int i = blockIdx.x * blockDim.x + threadIdx.x;
    if (i < NN * DD) { float v = x[i]; hb[i] = v; hbfA[i] = (__bf16)v; }
    if (i < 768 * 256) whhb[i] = (__bf16)w_hh[i];
    if (i < (NPAD - NN) * DD) {
        hbfA[NN * DD + i] = (__bf16)0.f;
        hbfB[NN * DD + i] = (__bf16)0.f;
    }
    if (i < NN) deg[i] = 0;
}

__global__ void hist_k(const int* __restrict__ dst, int* __restrict__ deg) {
    int e = blockIdx.x * blockDim.x + threadIdx.x;
    if (e < EE) atomicAdd(&deg[dst[e]], 1);
}

__global__ void scan_k(const int* __restrict__ deg, int* __restrict__ row_start,
                       int* __restrict__ cursor) {
    __shared__ int sums[1024];
    const int CH = 10;
    int t = threadIdx.x;
    int base = t * CH;
    int loc[CH];
    int s = 0;
#pragma unroll
    for (int i = 0; i < CH; i++) {
        int v = (base + i < NN) ? deg[base + i] : 0;
        loc[i] = s;
        s += v;
    }
    sums[t] = s;
    __syncthreads();
    for (int off = 1; off < 1024; off <<= 1) {
        int v = (t >= off) ? sums[t - off] : 0;
        __syncthreads();
        sums[t] += v;
        __syncthreads();
    }
    int pre = (t == 0) ? 0 : sums[t - 1];
#pragma unroll
    for (int i = 0; i < CH; i++) {
        int idx = base + i;
        if (idx < NN) {
            int v = pre + loc[i];
            row_start[idx] = v;
            cursor[idx] = v;
        }
    }
    if (t == 1023) row_start[NN] = sums[1023];
}

__global__ void fill_k(const int* __restrict__ ei, const float* __restrict__ attr,
                       int* __restrict__ cursor, int* __restrict__ ssrc,
                       float* __restrict__ sattr) {
    int e = blockIdx.x * blockDim.x + threadIdx.x;
    if (e < EE) {
        int dv = ei[EE + e];
        int p = atomicAdd(&cursor[dv], 1);
        ssrc[p] = ei[e];
        sattr[p] = attr[e];
    }
}

// ---------------- beff[l][j][t] = sum_d w_ih[j][d] * W[l][t][d], PURE FP32 ----------------

__global__ __launch_bounds__(256)
void beff32_k(const float* __restrict__ wih, const float* __restrict__ W,
              __bf16* __restrict__ beff) {
    __shared__ float As[16][68];
    __shared__ float Bs[16][68];
    int l = blockIdx.z;
    const float* Wl = W + (size_t)l * DD * DD;
    __bf16* Cl = beff + (size_t)l * 768 * DD;
    int tid = threadIdx.x;
    int tx = tid & 15, ty = tid >> 4;
    int jBase = blockIdx.x * 64;
    int tBase = blockIdx.y * 64;
    int lr = tid >> 2, lq = tid & 3;
    float acc[4][4];
#pragma unroll
    for (int i = 0; i < 4; i++)
#pragma unroll
        for (int j = 0; j < 4; j++) acc[i][j] = 0.f;

    for (int k0 = 0; k0 < DD; k0 += 16) {
        float4 av = *(const float4*)(wih + (size_t)(jBase + lr) * DD + k0 + lq * 4);
        float4 bv = *(const float4*)(Wl + (size_t)(tBase + lr) * DD + k0 + lq * 4);
        __syncthreads();
        As[lq * 4 + 0][lr] = av.x; As[lq * 4 + 1][lr] = av.y;
        As[lq * 4 + 2][lr] = av.z; As[lq * 4 + 3][lr] = av.w;
        Bs[lq * 4 + 0][lr] = bv.x; Bs[lq * 4 + 1][lr] = bv.y;
        Bs[lq * 4 + 2][lr] = bv.z; Bs[lq * 4 + 3][lr] = bv.w;
        __syncthreads();
#pragma unroll
        for (int kk = 0; kk < 16; kk++) {
            float a0 = As[kk][ty * 4 + 0], a1 = As[kk][ty * 4 + 1];
            float a2 = As[kk][ty * 4 + 2], a3 = As[kk][ty * 4 + 3];
            float b0 = Bs[kk][tx * 4 + 0], b1 = Bs[kk][tx * 4 + 1];
            float b2 = Bs[kk][tx * 4 + 2], b3 = Bs[kk][tx * 4 + 3];
            acc[0][0] += a0 * b0; acc[0][1] += a0 * b1; acc[0][2] += a0 * b2; acc[0][3] += a0 * b3;
            acc[1][0] += a1 * b0; acc[1][1] += a1 * b1; acc[1][2] += a1 * b2; acc[1][3] += a1 * b3;
            acc[2][0] += a2 * b0; acc[2][1] += a2 * b1; acc[2][2] += a2 * b2; acc[2][3] += a2 * b3;
            acc[3][0] += a3 * b0; acc[3][1] += a3 * b1; acc[3][2] += a3 * b2; acc[3][3] += a3 * b3;
        }
    }
#pragma unroll
    for (int i = 0; i < 4; i++) {
        int j = jBase + ty * 4 + i;
        bf16x4 o;
        o[0] = (__bf16)acc[i][0]; o[1] = (__bf16)acc[i][1];
        o[2] = (__bf16)acc[i][2]; o[3] = (__bf16)acc[i][3];
        *(bf16x4*)(Cl + (size_t)j * DD + tBase + tx * 4) = o;
    }
}

// ---------------- fused layer: gather(agg->LDS) + 6-gate MFMA + GRU epilogue ----------------
// grid (157, 2), block 512 (8 waves). Block tile: 64 nodes x 128 d-cols.
// Phase 1: stage own 64 h-rows via global_load_lds; each wave gathers 8 nodes' agg
//          (identical loop/rounding as the standalone aggregate kernel) into LDS.
// Phase 2: barrier-free K-loop; A-frags from LDS [ksub][64][32], B direct from L2.
// wave tile: 16n (nf=wave&3) x 64d (cg=wave>>2), 6 gates, acc 96 VGPRs.

__global__ __launch_bounds__(512, 4)
void fused_layer_k(const __bf16* __restrict__ hbf, const float* __restrict__ hin,
                   const int* __restrict__ row_start, const int* __restrict__ ssrc,
                   const float* __restrict__ sattr,
                   const __bf16* __restrict__ bihw, const __bf16* __restrict__ whh,
                   const float* __restrict__ b_ih, const float* __restrict__ b_hh,
                   float* __restrict__ hout, __bf16* __restrict__ hbfout) {
    __shared__ __bf16 aggT[8][64][32];   // 32 KB: agg rows, k-chunked
    __shared__ __bf16 hT[8][64][32];     // 32 KB: own h rows, k-chunked
    __shared__ int sIdx[8][64];
    __shared__ float sAtt[8][64];

    int tid = threadIdx.x;
    int wave = tid >> 6, lane = tid & 63;
    int ln = lane & 15, quad = lane >> 4;
    int nodeBlock = blockIdx.x * 64;
    int r4 = lane >> 2;
    int kb = (lane & 3) * 8;

    // ---- stage own h rows (32 wave-insts total, 4 per wave) ----
#pragma unroll
    for (int ii = 0; ii < 4; ii++) {
        int idx = wave * 4 + ii;           // 0..31
        int rg = idx >> 3;                 // 0..3 (16-row group)
        int ksub = idx & 7;                // 0..7
        const __bf16* src = hbf + (size_t)(nodeBlock + rg * 16 + r4) * DD + ksub * 32 + kb;
        gload_lds16(src, &hT[ksub][rg * 16][0]);
    }

    // ---- gather agg for 8 nodes per wave ----
    int half = lane >> 5;
    int c8 = (lane & 31) * 8;
    int L = lane & 31;
    for (int nn = 0; nn < 8; nn++) {
        int nl = wave * 8 + nn;
        int n = nodeBlock + nl;
        float acc8[8] = {0.f, 0.f, 0.f, 0.f, 0.f, 0.f, 0.f, 0.f};
        if (n < NN) {
            int s0 = row_start[n], s1 = row_start[n + 1];
            for (int base = s0; base < s1; base += 64) {
                int cnt = min(64, s1 - base);
                if (lane < cnt) {
                    sIdx[wave][lane] = ssrc[base + lane];
                    sAtt[wave][lane] = sattr[base + lane];
                }
                int t = 0;
                for (; t + 8 <= cnt; t += 8) {
#pragma unroll
                    for (int u = 0; u < 4; u++) {
                        int e = t + u * 2 + half;
                        int s = sIdx[wave][e];
                        float ww = sAtt[wave][e];
                        bf16x8 v = *(const bf16x8*)(hbf + (size_t)s * DD + c8);
#pragma unroll
                        for (int i = 0; i < 8; i++) acc8[i] += (float)v[i] * ww;
                    }
                }
                for (; t + 2 <= cnt; t += 2) {
                    int e = t + half;
                    int s = sIdx[wave][e];
                    float ww = sAtt[wave][e];
                    bf16x8 v = *(const bf16x8*)(hbf + (size_t)s * DD + c8);
#pragma unroll
                    for (int i = 0; i < 8; i++) acc8[i] += (float)v[i] * ww;
                }
                if (t < cnt && half == 0) {
                    int s = sIdx[wave][t];
                    float ww = sAtt[wave][t];
                    bf16x8 v = *(const bf16x8*)(hbf + (size_t)s * DD + c8);
#pragma unroll
                    for (int i = 0; i < 8; i++) acc8[i] += (float)v[i] * ww;
                }
            }
#pragma unroll
            for (int i = 0; i < 8; i++) acc8[i] += __shfl_xor(acc8[i], 32, 64);
        }
        if (half == 0) {
            bf16x8 o;
#pragma unroll
            for (int i = 0; i < 8; i++) o[i] = (__bf16)acc8[i];
            // c8 = L*8 spans one 32-chunk: chunk L>>2, offset (L&3)*8
            *(bf16x8*)&aggT[L >> 2][nl][(L & 3) * 8] = o;
        }
    }
    __syncthreads();   // drains global_load_lds (vmcnt) + LDS writes

    // ---- 6-gate MFMA, barrier-free; B direct from L2 ----
    int nf = wave & 3;            // node frag (16 rows)
    int cg = wave >> 2;           // col group (64 cols)
    int colAbs = blockIdx.y * 128 + cg * 64;

    f32x4 acc[6][4] = {};         // [gate][colFrag16]

    const __bf16* pI = bihw + (size_t)(colAbs + ln) * DD + quad * 8;
    const __bf16* pH = whh + (size_t)(colAbs + ln) * DD + quad * 8;

    for (int ksub = 0; ksub < 8; ksub++) {
        bf16x8 aA = *(const bf16x8*)&aggT[ksub][nf * 16 + ln][quad * 8];
        bf16x8 aH = *(const bf16x8*)&hT[ksub][nf * 16 + ln][quad * 8];
        int ko = ksub * 32;
#pragma unroll
        for (int g = 0; g < 3; g++) {
#pragma unroll
            for (int cc = 0; cc < 4; cc++) {
                size_t roff = (size_t)(g * 256 + cc * 16) * DD + ko;
                bf16x8 bI = *(const bf16x8*)(pI + roff);
                bf16x8 bH = *(const bf16x8*)(pH + roff);
                acc[g][cc] = __builtin_amdgcn_mfma_f32_16x16x32_bf16(aA, bI, acc[g][cc], 0, 0, 0);
                acc[3 + g][cc] = __builtin_amdgcn_mfma_f32_16x16x32_bf16(aH, bH, acc[3 + g][cc], 0, 0, 0);
            }
        }
    }

    // ---- GRU epilogue: 16n x 64d per wave ----
#pragma unroll
    for (int r = 0; r < 4; r++) {
        int n = nodeBlock + nf * 16 + quad * 4 + r;
        if (n >= NN) continue;
#pragma unroll
        for (int cc = 0; cc < 4; cc++) {
            int d = colAbs + cc * 16 + ln;
            float ir = acc[0][cc][r] + b_ih[d];
            float iz = acc[1][cc][r] + b_ih[d + 256];
            float in_ = acc[2][cc][r] + b_ih[d + 512];
            float hr = acc[3][cc][r] + b_hh[d];
            float hz = acc[4][cc][r] + b_hh[d + 256];
            float hn = acc[5][cc][r] + b_hh[d + 512];
            float rr = 1.f / (1.f + __expf(-(ir + hr)));
            float zz = 1.f / (1.f + __expf(-(iz + hz)));
            float ax = in_ + rr * hn;
            float e2 = __expf(-2.f * ax);
            float nnv = 2.f / (1.f + e2) - 1.f;
            float hp = hin[(size_t)n * DD + d];
            float o = (1.f - zz) * nnv + zz * hp;
            hout[(size_t)n * DD + d] = o;
            hbfout[(size_t)n * DD + d] = (__bf16)o;
        }
    }
}

// ---------------- launch ----------------

extern "C" void kernel_launch(void* const* d_in, const int* in_sizes, int n_in,
                              void* d_out, int out_size, void* d_ws, size_t ws_size,
                              hipStream_t stream) {
    const float* x = (const float*)d_in[0];
    const int* edge_index = (const int*)d_in[1];
    const float* edge_attr = (const float*)d_in[2];
    const float* weight = (const float*)d_in[3];
    const float* w_ih = (const float*)d_in[4];
    const float* w_hh = (const float*)d_in[5];
    const float* b_ih = (const float*)d_in[6];
    const float* b_hh = (const float*)d_in[7];

    size_t off = 0;
    char* base = (char*)d_ws;
    auto carve = [&](size_t bytes) -> void* {
        void* p = base + off;
        off += (bytes + 255) & ~(size_t)255;
        return p;
    };
    float* hb = (float*)carve((size_t)NPAD * DD * 4);
    __bf16* hbfA = (__bf16*)carve((size_t)NPAD * DD * 2);
    __bf16* hbfB = (__bf16*)carve((size_t)NPAD * DD * 2);
    __bf16* whhb = (__bf16*)carve((size_t)768 * DD * 2);
    __bf16* beff = (__bf16*)carve((size_t)LL * 768 * DD * 2);
    int* deg = (int*)carve((size_t)NN * 4);
    int* row_start = (int*)carve((size_t)(NN + 1) * 4);
    int* cursor = (int*)carve((size_t)NN * 4);
    int* ssrc = (int*)carve((size_t)EE * 4);
    float* sattr = (float*)carve((size_t)EE * 4);
    (void)ws_size;

    // setup (5 launches)
    prep_k<<<(NN * DD + 255) / 256, 256, 0, stream>>>(w_hh, x, whhb, hb, hbfA, hbfB, deg);
    hist_k<<<(EE + 255) / 256, 256, 0, stream>>>(edge_index + EE, deg);
    scan_k<<<1, 1024, 0, stream>>>(deg, row_start, cursor);
    fill_k<<<(EE + 255) / 256, 256, 0, stream>>>(edge_index, edge_attr, cursor, ssrc, sattr);
    beff32_k<<<dim3(12, 4, LL), 256, 0, stream>>>(w_ih, weight, beff);

    // layer loop: ONE dispatch per layer
    float* hA = hb;
    float* hB = (float*)d_out;
    __bf16* hbfIn = hbfA;
    __bf16* hbfOut = hbfB;
    for (int l = 0; l < LL; l++) {
        fused_layer_k<<<dim3(157, 2), 512, 0, stream>>>(hbfIn, hA, row_start, ssrc, sattr,
                                                        beff + (size_t)l * 768 * DD, whhb,
                                                        b_ih, b_hh, hB, hbfOut);
        float* t = hA; hA = hB; hB = t;
        __bf16* tb = hbfIn; hbfIn = hbfOut; hbfOut = tb;
    }
    // 5 swaps: final h landed in d_out
}

// Round 12
// 928.221 us; speedup vs baseline: 1.1340x; 1.1340x over previous
//
#include <hip/hip_runtime.h>
#include <hip/hip_bf16.h>

#define NN 10000
#define NPAD 10048   // 157 * 64
#define EE 320000
#define DD 256
#define LL 5

typedef __bf16 bf16x8 __attribute__((ext_vector_type(8)));
typedef __bf16 bf16x4 __attribute__((ext_vector_type(4)));
typedef float f32x4 __attribute__((ext_vector_type(4)));

__device__ __forceinline__ void gload_lds16(const void* g, void* l) {
    __builtin_amdgcn_global_load_lds(
        (const __attribute__((address_space(1))) void*)g,
        (__attribute__((address_space(3))) void*)l, 16, 0, 0);
}

// ---------------- setup kernels ----------------

// merged elementwise prep: whh conv, x conv, pad-zero, deg-zero
__global__ void prep_k(const float* __restrict__ w_hh, const float* __restrict__ x,
                       __bf16* __restrict__ whhb,
                       float* __restrict__ hb, __bf16* __restrict__ hbfA,
                       __bf16* __restrict__ hbfB, int* __restrict__ deg) {
    int i = blockIdx.x * blockDim.x + threadIdx.x;
    if (i < NN * DD) { float v = x[i]; hb[i] = v; hbfA[i] = (__bf16)v; }
    if (i < 768 * 256) whhb[i] = (__bf16)w_hh[i];
    if (i < (NPAD - NN) * DD) {
        hbfA[NN * DD + i] = (__bf16)0.f;
        hbfB[NN * DD + i] = (__bf16)0.f;
    }
    if (i < NN) deg[i] = 0;
}

__global__ void hist_k(const int* __restrict__ dst, int* __restrict__ deg) {
    int e = blockIdx.x * blockDim.x + threadIdx.x;
    if (e < EE) atomicAdd(&deg[dst[e]], 1);
}

__global__ void scan_k(const int* __restrict__ deg, int* __restrict__ row_start,
                       int* __restrict__ cursor) {
    __shared__ int sums[1024];
    const int CH = 10;
    int t = threadIdx.x;
    int base = t * CH;
    int loc[CH];
    int s = 0;
#pragma unroll
    for (int i = 0; i < CH; i++) {
        int v = (base + i < NN) ? deg[base + i] : 0;
        loc[i] = s;
        s += v;
    }
    sums[t] = s;
    __syncthreads();
    for (int off = 1; off < 1024; off <<= 1) {
        int v = (t >= off) ? sums[t - off] : 0;
        __syncthreads();
        sums[t] += v;
        __syncthreads();
    }
    int pre = (t == 0) ? 0 : sums[t - 1];
#pragma unroll
    for (int i = 0; i < CH; i++) {
        int idx = base + i;
        if (idx < NN) {
            int v = pre + loc[i];
            row_start[idx] = v;
            cursor[idx] = v;
        }
    }
    if (t == 1023) row_start[NN] = sums[1023];
}

__global__ void fill_k(const int* __restrict__ ei, const float* __restrict__ attr,
                       int* __restrict__ cursor, int* __restrict__ ssrc,
                       float* __restrict__ sattr) {
    int e = blockIdx.x * blockDim.x + threadIdx.x;
    if (e < EE) {
        int dv = ei[EE + e];
        int p = atomicAdd(&cursor[dv], 1);
        ssrc[p] = ei[e];
        sattr[p] = attr[e];
    }
}

// ---------------- beff[l][j][t] = sum_d w_ih[j][d] * W[l][t][d], PURE FP32 ----------------

__global__ __launch_bounds__(256)
void beff32_k(const float* __restrict__ wih, const float* __restrict__ W,
              __bf16* __restrict__ beff) {
    __shared__ float As[16][68];
    __shared__ float Bs[16][68];
    int l = blockIdx.z;
    const float* Wl = W + (size_t)l * DD * DD;
    __bf16* Cl = beff + (size_t)l * 768 * DD;
    int tid = threadIdx.x;
    int tx = tid & 15, ty = tid >> 4;
    int jBase = blockIdx.x * 64;
    int tBase = blockIdx.y * 64;
    int lr = tid >> 2, lq = tid & 3;
    float acc[4][4];
#pragma unroll
    for (int i = 0; i < 4; i++)
#pragma unroll
        for (int j = 0; j < 4; j++) acc[i][j] = 0.f;

    for (int k0 = 0; k0 < DD; k0 += 16) {
        float4 av = *(const float4*)(wih + (size_t)(jBase + lr) * DD + k0 + lq * 4);
        float4 bv = *(const float4*)(Wl + (size_t)(tBase + lr) * DD + k0 + lq * 4);
        __syncthreads();
        As[lq * 4 + 0][lr] = av.x; As[lq * 4 + 1][lr] = av.y;
        As[lq * 4 + 2][lr] = av.z; As[lq * 4 + 3][lr] = av.w;
        Bs[lq * 4 + 0][lr] = bv.x; Bs[lq * 4 + 1][lr] = bv.y;
        Bs[lq * 4 + 2][lr] = bv.z; Bs[lq * 4 + 3][lr] = bv.w;
        __syncthreads();
#pragma unroll
        for (int kk = 0; kk < 16; kk++) {
            float a0 = As[kk][ty * 4 + 0], a1 = As[kk][ty * 4 + 1];
            float a2 = As[kk][ty * 4 + 2], a3 = As[kk][ty * 4 + 3];
            float b0 = Bs[kk][tx * 4 + 0], b1 = Bs[kk][tx * 4 + 1];
            float b2 = Bs[kk][tx * 4 + 2], b3 = Bs[kk][tx * 4 + 3];
            acc[0][0] += a0 * b0; acc[0][1] += a0 * b1; acc[0][2] += a0 * b2; acc[0][3] += a0 * b3;
            acc[1][0] += a1 * b0; acc[1][1] += a1 * b1; acc[1][2] += a1 * b2; acc[1][3] += a1 * b3;
            acc[2][0] += a2 * b0; acc[2][1] += a2 * b1; acc[2][2] += a2 * b2; acc[2][3] += a2 * b3;
            acc[3][0] += a3 * b0; acc[3][1] += a3 * b1; acc[3][2] += a3 * b2; acc[3][3] += a3 * b3;
        }
    }
#pragma unroll
    for (int i = 0; i < 4; i++) {
        int j = jBase + ty * 4 + i;
        bf16x4 o;
        o[0] = (__bf16)acc[i][0]; o[1] = (__bf16)acc[i][1];
        o[2] = (__bf16)acc[i][2]; o[3] = (__bf16)acc[i][3];
        *(bf16x4*)(Cl + (size_t)j * DD + tBase + tx * 4) = o;
    }
}

// ---------------- fused layer: gather(agg->LDS) + 6-gate MFMA + GRU epilogue ----------------
// grid (157, 2), block 512 (8 waves). Block tile: 64 nodes x 128 d-cols.
// NOTE R12: __launch_bounds__(512) ONLY — R11's (512,4) forced 64 VGPRs -> 217 MB of
// scratch spill (WRITE_SIZE 232 MB, MfmaUtil 1.6%). acc[6][4] needs ~96 VGPRs; let the
// allocator take ~160-200 (2 waves/SIMD, LDS 68KB -> <=2 blocks/CU anyway).

__global__ __launch_bounds__(512)
void fused_layer_k(const __bf16* __restrict__ hbf, const float* __restrict__ hin,
                   const int* __restrict__ row_start, const int* __restrict__ ssrc,
                   const float* __restrict__ sattr,
                   const __bf16* __restrict__ bihw, const __bf16* __restrict__ whh,
                   const float* __restrict__ b_ih, const float* __restrict__ b_hh,
                   float* __restrict__ hout, __bf16* __restrict__ hbfout) {
    __shared__ __bf16 aggT[8][64][32];   // 32 KB: agg rows, k-chunked
    __shared__ __bf16 hT[8][64][32];     // 32 KB: own h rows, k-chunked
    __shared__ int sIdx[8][64];
    __shared__ float sAtt[8][64];

    int tid = threadIdx.x;
    int wave = tid >> 6, lane = tid & 63;
    int ln = lane & 15, quad = lane >> 4;
    int nodeBlock = blockIdx.x * 64;
    int r4 = lane >> 2;
    int kb = (lane & 3) * 8;

    // ---- stage own h rows (32 wave-insts total, 4 per wave) ----
#pragma unroll
    for (int ii = 0; ii < 4; ii++) {
        int idx = wave * 4 + ii;           // 0..31
        int rg = idx >> 3;                 // 0..3 (16-row group)
        int ksub = idx & 7;                // 0..7
        const __bf16* src = hbf + (size_t)(nodeBlock + rg * 16 + r4) * DD + ksub * 32 + kb;
        gload_lds16(src, &hT[ksub][rg * 16][0]);
    }

    // ---- gather agg for 8 nodes per wave ----
    int half = lane >> 5;
    int c8 = (lane & 31) * 8;
    int L = lane & 31;
    for (int nn = 0; nn < 8; nn++) {
        int nl = wave * 8 + nn;
        int n = nodeBlock + nl;
        float acc8[8] = {0.f, 0.f, 0.f, 0.f, 0.f, 0.f, 0.f, 0.f};
        if (n < NN) {
            int s0 = row_start[n], s1 = row_start[n + 1];
            for (int base = s0; base < s1; base += 64) {
                int cnt = min(64, s1 - base);
                if (lane < cnt) {
                    sIdx[wave][lane] = ssrc[base + lane];
                    sAtt[wave][lane] = sattr[base + lane];
                }
                int t = 0;
                for (; t + 8 <= cnt; t += 8) {
#pragma unroll
                    for (int u = 0; u < 4; u++) {
                        int e = t + u * 2 + half;
                        int s = sIdx[wave][e];
                        float ww = sAtt[wave][e];
                        bf16x8 v = *(const bf16x8*)(hbf + (size_t)s * DD + c8);
#pragma unroll
                        for (int i = 0; i < 8; i++) acc8[i] += (float)v[i] * ww;
                    }
                }
                for (; t + 2 <= cnt; t += 2) {
                    int e = t + half;
                    int s = sIdx[wave][e];
                    float ww = sAtt[wave][e];
                    bf16x8 v = *(const bf16x8*)(hbf + (size_t)s * DD + c8);
#pragma unroll
                    for (int i = 0; i < 8; i++) acc8[i] += (float)v[i] * ww;
                }
                if (t < cnt && half == 0) {
                    int s = sIdx[wave][t];
                    float ww = sAtt[wave][t];
                    bf16x8 v = *(const bf16x8*)(hbf + (size_t)s * DD + c8);
#pragma unroll
                    for (int i = 0; i < 8; i++) acc8[i] += (float)v[i] * ww;
                }
            }
#pragma unroll
            for (int i = 0; i < 8; i++) acc8[i] += __shfl_xor(acc8[i], 32, 64);
        }
        if (half == 0) {
            bf16x8 o;
#pragma unroll
            for (int i = 0; i < 8; i++) o[i] = (__bf16)acc8[i];
            // c8 = L*8 spans one 32-chunk: chunk L>>2, offset (L&3)*8
            *(bf16x8*)&aggT[L >> 2][nl][(L & 3) * 8] = o;
        }
    }
    __syncthreads();   // drains global_load_lds (vmcnt) + LDS writes

    // ---- 6-gate MFMA, barrier-free; B direct from L2 ----
    int nf = wave & 3;            // node frag (16 rows)
    int cg = wave >> 2;           // col group (64 cols)
    int colAbs = blockIdx.y * 128 + cg * 64;

    f32x4 acc[6][4] = {};         // [gate][colFrag16]

    const __bf16* pI = bihw + (size_t)(colAbs + ln) * DD + quad * 8;
    const __bf16* pH = whh + (size_t)(colAbs + ln) * DD + quad * 8;

    for (int ksub = 0; ksub < 8; ksub++) {
        bf16x8 aA = *(const bf16x8*)&aggT[ksub][nf * 16 + ln][quad * 8];
        bf16x8 aH = *(const bf16x8*)&hT[ksub][nf * 16 + ln][quad * 8];
        int ko = ksub * 32;
#pragma unroll
        for (int g = 0; g < 3; g++) {
#pragma unroll
            for (int cc = 0; cc < 4; cc++) {
                size_t roff = (size_t)(g * 256 + cc * 16) * DD + ko;
                bf16x8 bI = *(const bf16x8*)(pI + roff);
                bf16x8 bH = *(const bf16x8*)(pH + roff);
                acc[g][cc] = __builtin_amdgcn_mfma_f32_16x16x32_bf16(aA, bI, acc[g][cc], 0, 0, 0);
                acc[3 + g][cc] = __builtin_amdgcn_mfma_f32_16x16x32_bf16(aH, bH, acc[3 + g][cc], 0, 0, 0);
            }
        }
    }

    // ---- GRU epilogue: 16n x 64d per wave ----
#pragma unroll
    for (int r = 0; r < 4; r++) {
        int n = nodeBlock + nf * 16 + quad * 4 + r;
        if (n >= NN) continue;
#pragma unroll
        for (int cc = 0; cc < 4; cc++) {
            int d = colAbs + cc * 16 + ln;
            float ir = acc[0][cc][r] + b_ih[d];
            float iz = acc[1][cc][r] + b_ih[d + 256];
            float in_ = acc[2][cc][r] + b_ih[d + 512];
            float hr = acc[3][cc][r] + b_hh[d];
            float hz = acc[4][cc][r] + b_hh[d + 256];
            float hn = acc[5][cc][r] + b_hh[d + 512];
            float rr = 1.f / (1.f + __expf(-(ir + hr)));
            float zz = 1.f / (1.f + __expf(-(iz + hz)));
            float ax = in_ + rr * hn;
            float e2 = __expf(-2.f * ax);
            float nnv = 2.f / (1.f + e2) - 1.f;
            float hp = hin[(size_t)n * DD + d];
            float o = (1.f - zz) * nnv + zz * hp;
            hout[(size_t)n * DD + d] = o;
            hbfout[(size_t)n * DD + d] = (__bf16)o;
        }
    }
}

// ---------------- launch ----------------

extern "C" void kernel_launch(void* const* d_in, const int* in_sizes, int n_in,
                              void* d_out, int out_size, void* d_ws, size_t ws_size,
                              hipStream_t stream) {
    const float* x = (const float*)d_in[0];
    const int* edge_index = (const int*)d_in[1];
    const float* edge_attr = (const float*)d_in[2];
    const float* weight = (const float*)d_in[3];
    const float* w_ih = (const float*)d_in[4];
    const float* w_hh = (const float*)d_in[5];
    const float* b_ih = (const float*)d_in[6];
    const float* b_hh = (const float*)d_in[7];

    size_t off = 0;
    char* base = (char*)d_ws;
    auto carve = [&](size_t bytes) -> void* {
        void* p = base + off;
        off += (bytes + 255) & ~(size_t)255;
        return p;
    };
    float* hb = (float*)carve((size_t)NPAD * DD * 4);
    __bf16* hbfA = (__bf16*)carve((size_t)NPAD * DD * 2);
    __bf16* hbfB = (__bf16*)carve((size_t)NPAD * DD * 2);
    __bf16* whhb = (__bf16*)carve((size_t)768 * DD * 2);
    __bf16* beff = (__bf16*)carve((size_t)LL * 768 * DD * 2);
    int* deg = (int*)carve((size_t)NN * 4);
    int* row_start = (int*)carve((size_t)(NN + 1) * 4);
    int* cursor = (int*)carve((size_t)NN * 4);
    int* ssrc = (int*)carve((size_t)EE * 4);
    float* sattr = (float*)carve((size_t)EE * 4);
    (void)ws_size;

    // setup (5 launches)
    prep_k<<<(NN * DD + 255) / 256, 256, 0, stream>>>(w_hh, x, whhb, hb, hbfA, hbfB, deg);
    hist_k<<<(EE + 255) / 256, 256, 0, stream>>>(edge_index + EE, deg);
    scan_k<<<1, 1024, 0, stream>>>(deg, row_start, cursor);
    fill_k<<<(EE + 255) / 256, 256, 0, stream>>>(edge_index, edge_attr, cursor, ssrc, sattr);
    beff32_k<<<dim3(12, 4, LL), 256, 0, stream>>>(w_ih, weight, beff);

    // layer loop: ONE dispatch per layer
    float* hA = hb;
    float* hB = (float*)d_out;
    __bf16* hbfIn = hbfA;
    __bf16* hbfOut = hbfB;
    for (int l = 0; l < LL; l++) {
        fused_layer_k<<<dim3(157, 2), 512, 0, stream>>>(hbfIn, hA, row_start, ssrc, sattr,
                                                        beff + (size_t)l * 768 * DD, whhb,
                                                        b_ih, b_hh, hB, hbfOut);
        float* t = hA; hA = hB; hB = t;
        __bf16* tb = hbfIn; hbfIn = hbfOut; hbfOut = tb;
    }
    // 5 swaps: final h landed in d_out
}

// Round 13
// 339.888 us; speedup vs baseline: 3.0969x; 2.7310x over previous
//
#include <hip/hip_runtime.h>
#include <hip/hip_bf16.h>

#define NN 10000
#define NPAD 10048   // 157 * 64
#define EE 320000
#define DD 256
#define LL 5

typedef __bf16 bf16x8 __attribute__((ext_vector_type(8)));
typedef __bf16 bf16x4 __attribute__((ext_vector_type(4)));
typedef float f32x4 __attribute__((ext_vector_type(4)));

__device__ __forceinline__ void gload_lds16(const void* g, void* l) {
    __builtin_amdgcn_global_load_lds(
        (const __attribute__((address_space(1))) void*)g,
        (__attribute__((address_space(3))) void*)l, 16, 0, 0);
}

// ---------------- setup kernels ----------------

// merged elementwise prep: whh conv, x conv, pad-zero, deg-zero
__global__ void prep_k(const float* __restrict__ w_hh, const float* __restrict__ x,
                       __bf16* __restrict__ whhb,
                       float* __restrict__ hb, __bf16* __restrict__ hbfA,
                       __bf16* __restrict__ hbfB, __bf16* __restrict__ aggb,
                       int* __restrict__ deg) {
    int i = blockIdx.x * blockDim.x + threadIdx.x;
    if (i < NN * DD) { float v = x[i]; hb[i] = v; hbfA[i] = (__bf16)v; }
    if (i < 768 * 256) whhb[i] = (__bf16)w_hh[i];
    if (i < (NPAD - NN) * DD) {
        hbfA[NN * DD + i] = (__bf16)0.f;
        hbfB[NN * DD + i] = (__bf16)0.f;
        aggb[NN * DD + i] = (__bf16)0.f;
    }
    if (i < NN) deg[i] = 0;
}

__global__ void hist_k(const int* __restrict__ dst, int* __restrict__ deg) {
    int e = blockIdx.x * blockDim.x + threadIdx.x;
    if (e < EE) atomicAdd(&deg[dst[e]], 1);
}

__global__ void scan_k(const int* __restrict__ deg, int* __restrict__ row_start,
                       int* __restrict__ cursor) {
    __shared__ int sums[1024];
    const int CH = 10;
    int t = threadIdx.x;
    int base = t * CH;
    int loc[CH];
    int s = 0;
#pragma unroll
    for (int i = 0; i < CH; i++) {
        int v = (base + i < NN) ? deg[base + i] : 0;
        loc[i] = s;
        s += v;
    }
    sums[t] = s;
    __syncthreads();
    for (int off = 1; off < 1024; off <<= 1) {
        int v = (t >= off) ? sums[t - off] : 0;
        __syncthreads();
        sums[t] += v;
        __syncthreads();
    }
    int pre = (t == 0) ? 0 : sums[t - 1];
#pragma unroll
    for (int i = 0; i < CH; i++) {
        int idx = base + i;
        if (idx < NN) {
            int v = pre + loc[i];
            row_start[idx] = v;
            cursor[idx] = v;
        }
    }
    if (t == 1023) row_start[NN] = sums[1023];
}

// packed edge record: .x = src index, .y = attr bits (same fp32 value, bit-preserved)
__global__ void fill_k(const int* __restrict__ ei, const float* __restrict__ attr,
                       int* __restrict__ cursor, int2* __restrict__ edge) {
    int e = blockIdx.x * blockDim.x + threadIdx.x;
    if (e < EE) {
        int dv = ei[EE + e];
        int p = atomicAdd(&cursor[dv], 1);
        int2 rec;
        rec.x = ei[e];
        rec.y = __float_as_int(attr[e]);
        edge[p] = rec;
    }
}

// ---------------- beff[l][j][t] = sum_d w_ih[j][d] * W[l][t][d], PURE FP32 ----------------
// single rounding to bf16 at the end. [768x256]x[256x256] NT per layer; grid (12,4,L).

__global__ __launch_bounds__(256)
void beff32_k(const float* __restrict__ wih, const float* __restrict__ W,
              __bf16* __restrict__ beff) {
    __shared__ float As[16][68];
    __shared__ float Bs[16][68];
    int l = blockIdx.z;
    const float* Wl = W + (size_t)l * DD * DD;
    __bf16* Cl = beff + (size_t)l * 768 * DD;
    int tid = threadIdx.x;
    int tx = tid & 15, ty = tid >> 4;
    int jBase = blockIdx.x * 64;
    int tBase = blockIdx.y * 64;
    int lr = tid >> 2, lq = tid & 3;
    float acc[4][4];
#pragma unroll
    for (int i = 0; i < 4; i++)
#pragma unroll
        for (int j = 0; j < 4; j++) acc[i][j] = 0.f;

    for (int k0 = 0; k0 < DD; k0 += 16) {
        float4 av = *(const float4*)(wih + (size_t)(jBase + lr) * DD + k0 + lq * 4);
        float4 bv = *(const float4*)(Wl + (size_t)(tBase + lr) * DD + k0 + lq * 4);
        __syncthreads();
        As[lq * 4 + 0][lr] = av.x; As[lq * 4 + 1][lr] = av.y;
        As[lq * 4 + 2][lr] = av.z; As[lq * 4 + 3][lr] = av.w;
        Bs[lq * 4 + 0][lr] = bv.x; Bs[lq * 4 + 1][lr] = bv.y;
        Bs[lq * 4 + 2][lr] = bv.z; Bs[lq * 4 + 3][lr] = bv.w;
        __syncthreads();
#pragma unroll
        for (int kk = 0; kk < 16; kk++) {
            float a0 = As[kk][ty * 4 + 0], a1 = As[kk][ty * 4 + 1];
            float a2 = As[kk][ty * 4 + 2], a3 = As[kk][ty * 4 + 3];
            float b0 = Bs[kk][tx * 4 + 0], b1 = Bs[kk][tx * 4 + 1];
            float b2 = Bs[kk][tx * 4 + 2], b3 = Bs[kk][tx * 4 + 3];
            acc[0][0] += a0 * b0; acc[0][1] += a0 * b1; acc[0][2] += a0 * b2; acc[0][3] += a0 * b3;
            acc[1][0] += a1 * b0; acc[1][1] += a1 * b1; acc[1][2] += a1 * b2; acc[1][3] += a1 * b3;
            acc[2][0] += a2 * b0; acc[2][1] += a2 * b1; acc[2][2] += a2 * b2; acc[2][3] += a2 * b3;
            acc[3][0] += a3 * b0; acc[3][1] += a3 * b1; acc[3][2] += a3 * b2; acc[3][3] += a3 * b3;
        }
    }
#pragma unroll
    for (int i = 0; i < 4; i++) {
        int j = jBase + ty * 4 + i;
        bf16x4 o;
        o[0] = (__bf16)acc[i][0]; o[1] = (__bf16)acc[i][1];
        o[2] = (__bf16)acc[i][2]; o[3] = (__bf16)acc[i][3];
        *(bf16x4*)(Cl + (size_t)j * DD + tBase + tx * 4) = o;
    }
}

// ---------------- aggregation: agg_raw[n,:] = sum_{e: dst=n} h[src_e,:]*attr_e ----------------
// wave per node; packed-int2 edge staging to LDS; 2 edges per bf16x8 gather;
// shfl_xor(32) combine. Same accumulation order as R9 (bit-identical).

__global__ __launch_bounds__(256)
void aggregate_bf_k(const __bf16* __restrict__ hsrc, const int* __restrict__ row_start,
                    const int2* __restrict__ edge, __bf16* __restrict__ aggb) {
    __shared__ int2 sEdge[4][64];
    int w = threadIdx.x >> 6, lane = threadIdx.x & 63;
    int n = blockIdx.x * 4 + w;
    int s0 = row_start[n], s1 = row_start[n + 1];
    int half = lane >> 5;
    int c8 = (lane & 31) * 8;

    float acc[8] = {0.f, 0.f, 0.f, 0.f, 0.f, 0.f, 0.f, 0.f};

    for (int base = s0; base < s1; base += 64) {
        int cnt = min(64, s1 - base);
        if (lane < cnt) sEdge[w][lane] = edge[base + lane];
        int t = 0;
        for (; t + 8 <= cnt; t += 8) {
#pragma unroll
            for (int u = 0; u < 4; u++) {
                int e = t + u * 2 + half;
                int2 rec = sEdge[w][e];
                float ww = __int_as_float(rec.y);
                bf16x8 v = *(const bf16x8*)(hsrc + (size_t)rec.x * DD + c8);
#pragma unroll
                for (int i = 0; i < 8; i++) acc[i] += (float)v[i] * ww;
            }
        }
        for (; t + 2 <= cnt; t += 2) {
            int e = t + half;
            int2 rec = sEdge[w][e];
            float ww = __int_as_float(rec.y);
            bf16x8 v = *(const bf16x8*)(hsrc + (size_t)rec.x * DD + c8);
#pragma unroll
            for (int i = 0; i < 8; i++) acc[i] += (float)v[i] * ww;
        }
        if (t < cnt && half == 0) {
            int2 rec = sEdge[w][t];
            float ww = __int_as_float(rec.y);
            bf16x8 v = *(const bf16x8*)(hsrc + (size_t)rec.x * DD + c8);
#pragma unroll
            for (int i = 0; i < 8; i++) acc[i] += (float)v[i] * ww;
        }
    }

#pragma unroll
    for (int i = 0; i < 8; i++) acc[i] += __shfl_xor(acc[i], 32, 64);

    if (half == 0) {
        bf16x8 o;
#pragma unroll
        for (int i = 0; i < 8; i++) o[i] = (__bf16)acc[i];
        *(bf16x8*)(aggb + (size_t)n * DD + c8) = o;
    }
}

// ---------------- fused GRU: LDS-staged 6-gate MFMA + gate math (BK=32) ----------------
// i-gates use beff (= w_ih composed with W in fp32); h-gates use whh.
// block: 64 nodes x 64 d-cols, 4 waves (2x2); wave: 32n x 32d x 6 gates

__global__ __launch_bounds__(256, 2)
void gru_mfma_k(const __bf16* __restrict__ aggb, const __bf16* __restrict__ hbf,
                const float* __restrict__ hin,
                const __bf16* __restrict__ bihw, const __bf16* __restrict__ whh,
                const float* __restrict__ b_ih, const float* __restrict__ b_hh,
                float* __restrict__ hout, __bf16* __restrict__ hbfout) {
    __shared__ __bf16 sA[2][64][32];
    __shared__ __bf16 sB[6][64][32];
    int tid = threadIdx.x;
    int wave = tid >> 6, lane = tid & 63;
    int ln = lane & 15, quad = lane >> 4;
    int nodeBlock = blockIdx.x * 64;
    int colBlock = blockIdx.y * 64;
    int nodeHalf = (wave >> 1) * 32;
    int colHalf = (wave & 1) * 32;
    int r4 = lane >> 2;
    int kb = (lane & 3) * 8;

    f32x4 acc[6][2][2] = {};

    for (int k0 = 0; k0 < DD; k0 += 32) {
        __syncthreads();
#pragma unroll
        for (int ii = 0; ii < 8; ii++) {
            int idx = wave * 8 + ii;
            const __bf16* src;
            __bf16* dst;
            if (idx < 8) {
                int s = idx >> 2;
                int rg = idx & 3;
                const __bf16* A = s ? hbf : aggb;
                src = A + (size_t)(nodeBlock + rg * 16 + r4) * DD + k0 + kb;
                dst = &sA[s][rg * 16][0];
            } else {
                int j = idx - 8;
                int g6 = j >> 2;
                int rg = j & 3;
                const __bf16* B = (g6 < 3) ? bihw : whh;
                int brow = (g6 % 3) * 256 + colBlock + rg * 16 + r4;
                src = B + (size_t)brow * DD + k0 + kb;
                dst = &sB[g6][rg * 16][0];
            }
            gload_lds16(src, dst);
        }
        __syncthreads();

        bf16x8 aA[2], aH[2];
#pragma unroll
        for (int nf = 0; nf < 2; nf++) {
            aA[nf] = *(const bf16x8*)&sA[0][nodeHalf + nf * 16 + ln][quad * 8];
            aH[nf] = *(const bf16x8*)&sA[1][nodeHalf + nf * 16 + ln][quad * 8];
        }
#pragma unroll
        for (int g = 0; g < 3; g++) {
#pragma unroll
            for (int cc = 0; cc < 2; cc++) {
                bf16x8 bI = *(const bf16x8*)&sB[g][colHalf + cc * 16 + ln][quad * 8];
                bf16x8 bH = *(const bf16x8*)&sB[3 + g][colHalf + cc * 16 + ln][quad * 8];
#pragma unroll
                for (int nf = 0; nf < 2; nf++) {
                    acc[g][nf][cc] = __builtin_amdgcn_mfma_f32_16x16x32_bf16(aA[nf], bI, acc[g][nf][cc], 0, 0, 0);
                    acc[3 + g][nf][cc] = __builtin_amdgcn_mfma_f32_16x16x32_bf16(aH[nf], bH, acc[3 + g][nf][cc], 0, 0, 0);
                }
            }
        }
    }

    // epilogue
#pragma unroll
    for (int nf = 0; nf < 2; nf++) {
#pragma unroll
        for (int r = 0; r < 4; r++) {
            int n = nodeBlock + nodeHalf + nf * 16 + quad * 4 + r;
            if (n >= NN) continue;
#pragma unroll
            for (int cc = 0; cc < 2; cc++) {
                int d = colBlock + colHalf + cc * 16 + ln;
                float ir = acc[0][nf][cc][r] + b_ih[d];
                float iz = acc[1][nf][cc][r] + b_ih[d + 256];
                float in_ = acc[2][nf][cc][r] + b_ih[d + 512];
                float hr = acc[3][nf][cc][r] + b_hh[d];
                float hz = acc[4][nf][cc][r] + b_hh[d + 256];
                float hn = acc[5][nf][cc][r] + b_hh[d + 512];
                float rr = 1.f / (1.f + __expf(-(ir + hr)));
                float zz = 1.f / (1.f + __expf(-(iz + hz)));
                float ax = in_ + rr * hn;
                float e2 = __expf(-2.f * ax);
                float nnv = 2.f / (1.f + e2) - 1.f;
                float hp = hin[(size_t)n * DD + d];
                float o = (1.f - zz) * nnv + zz * hp;
                hout[(size_t)n * DD + d] = o;
                hbfout[(size_t)n * DD + d] = (__bf16)o;
            }
        }
    }
}

// ---------------- launch ----------------

extern "C" void kernel_launch(void* const* d_in, const int* in_sizes, int n_in,
                              void* d_out, int out_size, void* d_ws, size_t ws_size,
                              hipStream_t stream) {
    const float* x = (const float*)d_in[0];
    const int* edge_index = (const int*)d_in[1];
    const float* edge_attr = (const float*)d_in[2];
    const float* weight = (const float*)d_in[3];
    const float* w_ih = (const float*)d_in[4];
    const float* w_hh = (const float*)d_in[5];
    const float* b_ih = (const float*)d_in[6];
    const float* b_hh = (const float*)d_in[7];

    size_t off = 0;
    char* base = (char*)d_ws;
    auto carve = [&](size_t bytes) -> void* {
        void* p = base + off;
        off += (bytes + 255) & ~(size_t)255;
        return p;
    };
    float* hb = (float*)carve((size_t)NPAD * DD * 4);
    __bf16* hbfA = (__bf16*)carve((size_t)NPAD * DD * 2);
    __bf16* hbfB = (__bf16*)carve((size_t)NPAD * DD * 2);
    __bf16* aggb = (__bf16*)carve((size_t)NPAD * DD * 2);
    __bf16* whhb = (__bf16*)carve((size_t)768 * DD * 2);
    __bf16* beff = (__bf16*)carve((size_t)LL * 768 * DD * 2);
    int* deg = (int*)carve((size_t)NN * 4);
    int* row_start = (int*)carve((size_t)(NN + 1) * 4);
    int* cursor = (int*)carve((size_t)NN * 4);
    int2* edge = (int2*)carve((size_t)EE * 8);
    (void)ws_size;

    // setup (5 launches)
    prep_k<<<(NN * DD + 255) / 256, 256, 0, stream>>>(w_hh, x, whhb, hb, hbfA, hbfB,
                                                      aggb, deg);
    hist_k<<<(EE + 255) / 256, 256, 0, stream>>>(edge_index + EE, deg);
    scan_k<<<1, 1024, 0, stream>>>(deg, row_start, cursor);
    fill_k<<<(EE + 255) / 256, 256, 0, stream>>>(edge_index, edge_attr, cursor, edge);
    beff32_k<<<dim3(12, 4, LL), 256, 0, stream>>>(w_ih, weight, beff);

    // layer loop: wide gather dispatch + MFMA gate dispatch (proven best decomposition)
    float* hA = hb;
    float* hB = (float*)d_out;
    __bf16* hbfIn = hbfA;
    __bf16* hbfOut = hbfB;
    for (int l = 0; l < LL; l++) {
        aggregate_bf_k<<<2500, 256, 0, stream>>>(hbfIn, row_start, edge, aggb);
        gru_mfma_k<<<dim3(157, 4), 256, 0, stream>>>(aggb, hbfIn, hA,
                                                     beff + (size_t)l * 768 * DD, whhb,
                                                     b_ih, b_hh, hB, hbfOut);
        float* t = hA; hA = hB; hB = t;
        __bf16* tb = hbfIn; hbfIn = hbfOut; hbfOut = tb;
    }
    // 5 swaps: final h landed in d_out
}